// Round 4
// baseline (745.692 us; speedup 1.0000x reference)
//
#include <hip/hip_runtime.h>
#include <hip/hip_bf16.h>
#include <cstdint>
#include <cstddef>

// ---------------------------------------------------------------------------
// MaskedSelfAttention: B=2, T=2048, C=2048, NH=16, NG=4, D=128
// sliding window 512 + sink 4, RoPE base 10000, pos 0.
// Inputs/outputs fp32 (per reference dtypes); bf16 MFMA internally, fp32 acc.
// Workspace (32 MB): Qb[0,16M) Kb[16M,20M) Vt[20M,24M) At[24M,32M)  (bf16).
// ---------------------------------------------------------------------------

typedef short s16;
typedef short short8 __attribute__((ext_vector_type(8)));
typedef float f32x4  __attribute__((ext_vector_type(4)));

#define MFMA16(a, b, c) __builtin_amdgcn_mfma_f32_16x16x32_bf16((a), (b), (c), 0, 0, 0)

__device__ __forceinline__ float bf2f(s16 u) {
    union { float f; uint32_t i; } v;
    v.i = ((uint32_t)(uint16_t)u) << 16;
    return v.f;
}
__device__ __forceinline__ s16 f2bf(float f) {
    union { float f; uint32_t i; } v;
    v.f = f;
    uint32_t r = v.i + 0x7FFFu + ((v.i >> 16) & 1u);   // RNE
    return (s16)(r >> 16);
}

// ---------------------------------------------------------------------------
// GEMM: out[m][n] = sum_k A[m][k]*B[k][n] + bias[n]
// AF32: A is fp32 (else bf16). B always fp32 [K][N]. bias fp32.
// OF32: out fp32 (else bf16; transOut scatters out[n*ldout+m]).
// fp32 sources are converted to bf16 during LDS staging.
// Block 256 thr = 4 waves; tile 64x64, BK=32; wave = 32x32 via 2x2 MFMA.
// mfma_f32_16x16x32_bf16 layouts (verified m89/m91):
//   A-frag: A[m=lane&15][k=(lane>>4)*8+j]
//   B-frag: B[k=(lane>>4)*8+j][n=lane&15]
//   C/D:    row=(lane>>4)*4+reg, col=lane&15
// ---------------------------------------------------------------------------
template <bool AF32, bool OF32>
__global__ __launch_bounds__(256)
void gemm_k(const void* __restrict__ Ap, const float* __restrict__ B,
            const float* __restrict__ bias, void* __restrict__ outp,
            int M, int N, int K, int transOut, int ldout)
{
    __shared__ s16 As[64 * 40];   // [m][k], pad 40
    __shared__ s16 Bs[64 * 40];   // [n][k] after in-LDS transpose

    int tid  = threadIdx.x;
    int m0   = blockIdx.x * 64, n0 = blockIdx.y * 64;
    int lane = tid & 63, wv = tid >> 6;
    int wm   = (wv >> 1) * 32, wn = (wv & 1) * 32;
    int fr   = lane & 15, fq = lane >> 4;

    int sr  = tid >> 2, sc = (tid & 3) * 8;    // A staging: row 0..63, k-off
    int bkr = tid >> 3, bnc = (tid & 7) * 8;   // B staging: k-row 0..31, n-off

    f32x4 acc[2][2] = {};

    for (int k0 = 0; k0 < K; k0 += 32) {
        __syncthreads();
        // stage A tile (64 x 32) as bf16
        if (AF32) {
            const float* ag = (const float*)Ap + (size_t)(m0 + sr) * K + sc + k0;
            f32x4 f0 = *(const f32x4*)(ag);
            f32x4 f1 = *(const f32x4*)(ag + 4);
            short8 a8;
            a8[0]=f2bf(f0[0]); a8[1]=f2bf(f0[1]); a8[2]=f2bf(f0[2]); a8[3]=f2bf(f0[3]);
            a8[4]=f2bf(f1[0]); a8[5]=f2bf(f1[1]); a8[6]=f2bf(f1[2]); a8[7]=f2bf(f1[3]);
            *(short8*)&As[sr * 40 + sc] = a8;
        } else {
            const s16* ag = (const s16*)Ap + (size_t)(m0 + sr) * K + sc + k0;
            *(short8*)&As[sr * 40 + sc] = *(const short8*)(ag);
        }
        // stage B tile (32 x 64) transposed to [n][k], bf16
        {
            const float* bg = B + (size_t)(k0 + bkr) * N + n0 + bnc;
            f32x4 f0 = *(const f32x4*)(bg);
            f32x4 f1 = *(const f32x4*)(bg + 4);
            Bs[(bnc + 0) * 40 + bkr] = f2bf(f0[0]);
            Bs[(bnc + 1) * 40 + bkr] = f2bf(f0[1]);
            Bs[(bnc + 2) * 40 + bkr] = f2bf(f0[2]);
            Bs[(bnc + 3) * 40 + bkr] = f2bf(f0[3]);
            Bs[(bnc + 4) * 40 + bkr] = f2bf(f1[0]);
            Bs[(bnc + 5) * 40 + bkr] = f2bf(f1[1]);
            Bs[(bnc + 6) * 40 + bkr] = f2bf(f1[2]);
            Bs[(bnc + 7) * 40 + bkr] = f2bf(f1[3]);
        }
        __syncthreads();

        short8 a0 = *(const short8*)&As[(wm      + fr) * 40 + fq * 8];
        short8 a1 = *(const short8*)&As[(wm + 16 + fr) * 40 + fq * 8];
        short8 b0 = *(const short8*)&Bs[(wn      + fr) * 40 + fq * 8];
        short8 b1 = *(const short8*)&Bs[(wn + 16 + fr) * 40 + fq * 8];

        acc[0][0] = MFMA16(a0, b0, acc[0][0]);
        acc[0][1] = MFMA16(a0, b1, acc[0][1]);
        acc[1][0] = MFMA16(a1, b0, acc[1][0]);
        acc[1][1] = MFMA16(a1, b1, acc[1][1]);
    }

    for (int im = 0; im < 2; im++)
        for (int in = 0; in < 2; in++)
            for (int r = 0; r < 4; r++) {
                int m = m0 + wm + im * 16 + fq * 4 + r;
                int n = n0 + wn + in * 16 + fr;
                float v = acc[im][in][r] + bias[n];
                if (OF32) {
                    ((float*)outp)[(size_t)m * N + n] = v;
                } else if (transOut) {
                    ((s16*)outp)[(size_t)n * ldout + m] = f2bf(v);
                } else {
                    ((s16*)outp)[(size_t)m * N + n] = f2bf(v);
                }
            }
}

// ---------------------------------------------------------------------------
// RoPE in-place on bf16 buf [4096][nheads*128]; pairs (i, i+64); pos 0.
// cos/sin stay fp32 (reference: astype(float32)).
// ---------------------------------------------------------------------------
__global__ __launch_bounds__(256)
void rope_kernel(s16* __restrict__ buf, int nheads)
{
    int idx = blockIdx.x * 256 + threadIdx.x;
    int i   = idx & 63;
    int hi  = idx >> 6;
    int h   = hi % nheads;
    int row = hi / nheads;
    int t   = row & 2047;

    float inv_freq = (float)(1.0 / pow(10000.0, (double)i * (1.0 / 64.0)));
    float ang = (float)t * inv_freq;
    float c = cosf(ang);
    float s = sinf(ang);

    size_t base = (size_t)row * ((size_t)nheads * 128) + (size_t)h * 128 + i;
    float x1 = bf2f(buf[base]);
    float x2 = bf2f(buf[base + 64]);
    buf[base]      = f2bf(x1 * c - x2 * s);
    buf[base + 64] = f2bf(x1 * s + x2 * c);
}

// ---------------------------------------------------------------------------
// Flash attention with sliding window + sink, one batch per launch (bf16 I/O).
// Q:  [4096][2048] (row b*2048+t, col h*128+d), after RoPE
// Kb: [4096][512]  (col g*128+d), after RoPE
// Vt: [512][4096]  (row g*128+d, col b*2048+t)
// O:  [2048][2048] batch-local.
// Block 256 thr = 4 waves; 64 q rows of one h per block; wave = 16 rows.
// Key chunks of 32; chunk list = [0] ∪ [max(0,t0-512)/32 .. (t0+63)/32].
// ---------------------------------------------------------------------------
__global__ __launch_bounds__(256)
void attn_kernel(const s16* __restrict__ Q, const s16* __restrict__ Kb,
                 const s16* __restrict__ Vt, s16* __restrict__ O, int b)
{
    __shared__ s16 Ks[32][136];
    __shared__ s16 Vs[128][40];
    __shared__ s16 Ps[4][16][40];

    int h = blockIdx.y, g = h >> 2;
    int t0 = blockIdx.x * 64;
    int tid = threadIdx.x, lane = tid & 63, wv = tid >> 6;
    int fr = lane & 15, fq = lane >> 4;
    int tw = t0 + wv * 16;

    const float scale = 0.08838834764831845f;   // 128^-0.5
    const float NEG = -1e9f;

    short8 qf[4];
    {
        const s16* qrow = Q + (size_t)(b * 2048 + tw + fr) * 2048 + h * 128 + fq * 8;
        qf[0] = *(const short8*)(qrow);
        qf[1] = *(const short8*)(qrow + 32);
        qf[2] = *(const short8*)(qrow + 64);
        qf[3] = *(const short8*)(qrow + 96);
    }

    f32x4 Oacc[8] = {};
    float m_r[4], l_r[4];
    for (int r = 0; r < 4; r++) { m_r[r] = NEG; l_r[r] = 0.0f; }

    int lo = t0 - 512; if (lo < 0) lo = 0;
    int c0   = lo >> 5;
    int cend = (t0 + 63) >> 5;
    int nch  = cend - c0 + 1 + (c0 > 0 ? 1 : 0);

    for (int ic = 0; ic < nch; ic++) {
        int cc = (c0 > 0) ? (ic == 0 ? 0 : c0 + ic - 1) : ic;
        int kbase = cc * 32;

        __syncthreads();
        for (int it = 0; it < 2; it++) {
            int idx = it * 2048 + tid * 8;
            int kr = idx >> 7, kc = idx & 127;
            *(short8*)&Ks[kr][kc] =
                *(const short8*)(Kb + (size_t)(b * 2048 + kbase + kr) * 512 + g * 128 + kc);
        }
        for (int it = 0; it < 2; it++) {
            int idx = it * 2048 + tid * 8;
            int d = idx >> 5, kc = idx & 31;
            *(short8*)&Vs[d][kc] =
                *(const short8*)(Vt + (size_t)(g * 128 + d) * 4096 + b * 2048 + kbase + kc);
        }
        __syncthreads();

        float sv[2][4];
        for (int kn = 0; kn < 2; kn++) {
            f32x4 sc4 = {0.f, 0.f, 0.f, 0.f};
            for (int dc = 0; dc < 4; dc++) {
                short8 kf = *(const short8*)&Ks[kn * 16 + fr][dc * 32 + fq * 8];
                sc4 = MFMA16(qf[dc], kf, sc4);
            }
            int j = kbase + kn * 16 + fr;
            for (int r = 0; r < 4; r++) {
                int t = tw + fq * 4 + r;
                bool ok = (j <= t) && ((j >= t - 512) || (j < 4));
                sv[kn][r] = ok ? sc4[r] * scale : NEG;
            }
        }

        float alpha[4], p0[4], p1[4];
        for (int r = 0; r < 4; r++) {
            float cm = fmaxf(sv[0][r], sv[1][r]);
            for (int off = 1; off < 16; off <<= 1)
                cm = fmaxf(cm, __shfl_xor(cm, off));
            float nm = fmaxf(m_r[r], cm);
            alpha[r] = __expf(m_r[r] - nm);
            p0[r] = __expf(sv[0][r] - nm);
            p1[r] = __expf(sv[1][r] - nm);
            float ps = p0[r] + p1[r];
            for (int off = 1; off < 16; off <<= 1)
                ps += __shfl_xor(ps, off);
            l_r[r] = l_r[r] * alpha[r] + ps;
            m_r[r] = nm;
        }
        for (int n0 = 0; n0 < 8; n0++)
            for (int r = 0; r < 4; r++)
                Oacc[n0][r] *= alpha[r];

        for (int r = 0; r < 4; r++) {
            Ps[wv][fq * 4 + r][fr]      = f2bf(p0[r]);
            Ps[wv][fq * 4 + r][16 + fr] = f2bf(p1[r]);
        }
        __syncthreads();
        short8 pf = *(const short8*)&Ps[wv][fr][fq * 8];

        for (int n0 = 0; n0 < 8; n0++) {
            short8 vf = *(const short8*)&Vs[n0 * 16 + fr][fq * 8];
            Oacc[n0] = MFMA16(pf, vf, Oacc[n0]);
        }
    }

    float invl[4];
    for (int r = 0; r < 4; r++) invl[r] = 1.0f / l_r[r];
    for (int n0 = 0; n0 < 8; n0++)
        for (int r = 0; r < 4; r++) {
            int t = tw + fq * 4 + r;
            O[(size_t)t * 2048 + h * 128 + n0 * 16 + fr] =
                f2bf(Oacc[n0][r] * invl[r]);
        }
}

// ---------------------------------------------------------------------------
// Launcher. Inputs fp32; output fp32. Workspace bf16:
//   Qb[0,16M) Kb[16M,20M) Vt[20M,24M) At[24M,32M)
// ---------------------------------------------------------------------------
extern "C" void kernel_launch(void* const* d_in, const int* in_sizes, int n_in,
                              void* d_out, int out_size, void* d_ws, size_t ws_size,
                              hipStream_t stream)
{
    const float* x  = (const float*)d_in[0];
    const float* Wq = (const float*)d_in[1];
    const float* bq = (const float*)d_in[2];
    const float* Wk = (const float*)d_in[3];
    const float* bk = (const float*)d_in[4];
    const float* Wv = (const float*)d_in[5];
    const float* bv = (const float*)d_in[6];
    const float* Wo = (const float*)d_in[7];
    const float* bo = (const float*)d_in[8];
    float* out = (float*)d_out;

    if (ws_size < 33554432) return;   // diagnostic: out stays 0 if ws too small

    char* ws = (char*)d_ws;
    s16* Qb = (s16*)(ws + 0);            // [4096][2048] bf16
    s16* Kb = (s16*)(ws + 16777216);     // [4096][512]
    s16* Vt = (s16*)(ws + 20971520);     // [512][4096]
    s16* At = (s16*)(ws + 25165824);     // [2048][2048], reused per batch

    // projections: fp32 in -> bf16 out
    gemm_k<true, false><<<dim3(64, 32), 256, 0, stream>>>(x, Wq, bq, Qb, 4096, 2048, 2048, 0, 0);
    gemm_k<true, false><<<dim3(64,  8), 256, 0, stream>>>(x, Wk, bk, Kb, 4096,  512, 2048, 0, 0);
    gemm_k<true, false><<<dim3(64,  8), 256, 0, stream>>>(x, Wv, bv, Vt, 4096,  512, 2048, 1, 4096);

    // RoPE on Q (16 heads) and K (4 heads)
    rope_kernel<<<16384, 256, 0, stream>>>(Qb, 16);
    rope_kernel<<< 4096, 256, 0, stream>>>(Kb, 4);

    // per-batch: attention then output projection (bf16 At -> fp32 out)
    for (int b = 0; b < 2; b++) {
        attn_kernel<<<dim3(32, 16), 256, 0, stream>>>(Qb, Kb, Vt, At, b);
        gemm_k<false, true><<<dim3(32, 32), 256, 0, stream>>>(At, Wo, bo,
                                                              out + (size_t)b * 4194304,
                                                              2048, 2048, 2048, 0, 0);
    }
}

// Round 5
// 577.851 us; speedup vs baseline: 1.2905x; 1.2905x over previous
//
#include <hip/hip_runtime.h>
#include <hip/hip_bf16.h>
#include <cstdint>
#include <cstddef>

// ---------------------------------------------------------------------------
// MaskedSelfAttention: B=2, T=2048, C=2048, NH=16, NG=4, D=128
// sliding window 512 + sink 4, RoPE base 10000, pos 0.
// fp32 I/O, bf16 MFMA internally (fp32 accum).
// Workspace (32 MB), time-multiplexed:
//   [0,8M):   Wqt -> (Wkt [0,2M), Wvt [2,4M)) -> Wot
//   [8,24M):  Qb [4096][2048] bf16; rows 0..2047 reused as At(b1) after b0
//   [24,28M): Kb [4096][512] bf16
//   [28,32M): Vt [512][4096] bf16
// At(b0) lives in d_out's batch-1 half (bf16 scratch, dead until O-GEMM b1).
// ---------------------------------------------------------------------------

typedef short s16;
typedef short short8 __attribute__((ext_vector_type(8)));
typedef float f32x4  __attribute__((ext_vector_type(4)));

#define MFMA16(a, b, c) __builtin_amdgcn_mfma_f32_16x16x32_bf16((a), (b), (c), 0, 0, 0)

__device__ __forceinline__ float bf2f(s16 u) {
    union { float f; uint32_t i; } v;
    v.i = ((uint32_t)(uint16_t)u) << 16;
    return v.f;
}
__device__ __forceinline__ s16 f2bf(float f) {
    union { float f; uint32_t i; } v;
    v.f = f;
    uint32_t r = v.i + 0x7FFFu + ((v.i >> 16) & 1u);   // RNE
    return (s16)(r >> 16);
}

// ---------------------------------------------------------------------------
// Transpose + cast: in fp32 [K][N] -> out bf16 [N][K].  32x32 tiles.
// ---------------------------------------------------------------------------
__global__ __launch_bounds__(256)
void castT(const float* __restrict__ in, s16* __restrict__ out, int K, int N)
{
    __shared__ float t[32][33];
    int n0 = blockIdx.x * 32, k0 = blockIdx.y * 32;
    int tx = threadIdx.x & 31, ty = threadIdx.x >> 5;   // ty 0..7
    for (int i = 0; i < 32; i += 8)
        t[ty + i][tx] = in[(size_t)(k0 + ty + i) * N + n0 + tx];
    __syncthreads();
    for (int i = 0; i < 32; i += 8)
        out[(size_t)(n0 + ty + i) * K + k0 + tx] = f2bf(t[tx][ty + i]);
}

// ---------------------------------------------------------------------------
// GEMM: out[m][n] = sum_k A[m][k] * Bt[n][k] + bias[n]
// Bt: bf16 [N][K] (pre-transposed weight). A: fp32 (AF32) or bf16.
// OF32: fp32 out; else bf16 (transOut scatters out[n*ldout+m]).
// Tile 128x128, BK=32, 256 thr = 4 waves, wave = 64x64 (4x4 MFMA frags).
// LDS: flat [row][32] bf16, 64-B rows (m97 lineage, no padding).
// mfma_f32_16x16x32_bf16 layouts (verified m89/m91):
//   A-frag: A[m=lane&15][k=(lane>>4)*8+j]; B-frag: B[k=(lane>>4)*8+j][n=lane&15]
//   C/D:    row=(lane>>4)*4+reg, col=lane&15
// ---------------------------------------------------------------------------
template <int AF32, int OF32>
__global__ __launch_bounds__(256)
void gemm128(const void* __restrict__ Ap, const s16* __restrict__ Bt,
             const float* __restrict__ bias, void* __restrict__ outp,
             int M, int N, int K, int transOut, int ldout)
{
    __shared__ s16 As[128 * 32];
    __shared__ s16 Bs[128 * 32];

    const int tid  = threadIdx.x;
    const int m0   = blockIdx.x * 128, n0 = blockIdx.y * 128;
    const int lane = tid & 63, wv = tid >> 6;
    const int wm   = (wv >> 1) * 64, wn = (wv & 1) * 64;
    const int fr   = lane & 15, fq = lane >> 4;

    // fragment LDS pointers: constant across the k-loop
    const s16* pa[4];
    const s16* pb[4];
    #pragma unroll
    for (int i = 0; i < 4; i++) {
        pa[i] = &As[(wm + i * 16 + fr) * 32 + fq * 8];
        pb[i] = &Bs[(wn + i * 16 + fr) * 32 + fq * 8];
    }

    // staging assignments
    const int am = tid >> 1, ak = (tid & 1) * 16;            // fp32-A path
    const int r1 = tid >> 2,        o1 = (tid & 3) * 8;      // chunk tid
    const int r2 = (tid + 256) >> 2, o2 = (tid & 3) * 8;     // chunk tid+256

    const float* Af = (const float*)Ap;
    const s16*   Ab = (const s16*)Ap;

    f32x4 acc[4][4] = {};

    for (int k0 = 0; k0 < K; k0 += 32) {
        __syncthreads();
        if (AF32) {
            const float* ag = Af + (size_t)(m0 + am) * K + k0 + ak;
            f32x4 f0 = *(const f32x4*)(ag);
            f32x4 f1 = *(const f32x4*)(ag + 4);
            f32x4 f2 = *(const f32x4*)(ag + 8);
            f32x4 f3 = *(const f32x4*)(ag + 12);
            short8 h0, h1;
            h0[0]=f2bf(f0[0]); h0[1]=f2bf(f0[1]); h0[2]=f2bf(f0[2]); h0[3]=f2bf(f0[3]);
            h0[4]=f2bf(f1[0]); h0[5]=f2bf(f1[1]); h0[6]=f2bf(f1[2]); h0[7]=f2bf(f1[3]);
            h1[0]=f2bf(f2[0]); h1[1]=f2bf(f2[1]); h1[2]=f2bf(f2[2]); h1[3]=f2bf(f2[3]);
            h1[4]=f2bf(f3[0]); h1[5]=f2bf(f3[1]); h1[6]=f2bf(f3[2]); h1[7]=f2bf(f3[3]);
            *(short8*)&As[am * 32 + ak]     = h0;
            *(short8*)&As[am * 32 + ak + 8] = h1;
        } else {
            *(short8*)&As[r1 * 32 + o1] = *(const short8*)(Ab + (size_t)(m0 + r1) * K + k0 + o1);
            *(short8*)&As[r2 * 32 + o2] = *(const short8*)(Ab + (size_t)(m0 + r2) * K + k0 + o2);
        }
        *(short8*)&Bs[r1 * 32 + o1] = *(const short8*)(Bt + (size_t)(n0 + r1) * K + k0 + o1);
        *(short8*)&Bs[r2 * 32 + o2] = *(const short8*)(Bt + (size_t)(n0 + r2) * K + k0 + o2);
        __syncthreads();

        short8 af[4], bf[4];
        #pragma unroll
        for (int i = 0; i < 4; i++) af[i] = *(const short8*)pa[i];
        #pragma unroll
        for (int i = 0; i < 4; i++) bf[i] = *(const short8*)pb[i];

        #pragma unroll
        for (int mi = 0; mi < 4; mi++)
            #pragma unroll
            for (int ni = 0; ni < 4; ni++)
                acc[mi][ni] = MFMA16(af[mi], bf[ni], acc[mi][ni]);
    }

    #pragma unroll
    for (int mi = 0; mi < 4; mi++)
        #pragma unroll
        for (int ni = 0; ni < 4; ni++)
            #pragma unroll
            for (int r = 0; r < 4; r++) {
                int m = m0 + wm + mi * 16 + fq * 4 + r;
                int n = n0 + wn + ni * 16 + fr;
                float v = acc[mi][ni][r] + bias[n];
                if (OF32) {
                    ((float*)outp)[(size_t)m * N + n] = v;
                } else if (transOut) {
                    ((s16*)outp)[(size_t)n * ldout + m] = f2bf(v);
                } else {
                    ((s16*)outp)[(size_t)m * N + n] = f2bf(v);
                }
            }
}

// ---------------------------------------------------------------------------
// RoPE in-place on bf16 buf [4096][nheads*128]; pairs (i, i+64); pos 0.
// cos/sin fp32 (reference keeps them fp32 for fp32 inputs).
// ---------------------------------------------------------------------------
__global__ __launch_bounds__(256)
void rope_kernel(s16* __restrict__ buf, int nheads)
{
    int idx = blockIdx.x * 256 + threadIdx.x;
    int i   = idx & 63;
    int hi  = idx >> 6;
    int h   = hi % nheads;
    int row = hi / nheads;
    int t   = row & 2047;

    float inv_freq = (float)(1.0 / pow(10000.0, (double)i * (1.0 / 64.0)));
    float ang = (float)t * inv_freq;
    float c = cosf(ang);
    float s = sinf(ang);

    size_t base = (size_t)row * ((size_t)nheads * 128) + (size_t)h * 128 + i;
    float x1 = bf2f(buf[base]);
    float x2 = bf2f(buf[base + 64]);
    buf[base]      = f2bf(x1 * c - x2 * s);
    buf[base + 64] = f2bf(x1 * s + x2 * c);
}

// ---------------------------------------------------------------------------
// Flash attention with sliding window + sink, one batch per launch (bf16 I/O).
// Q [4096][2048] (row b*2048+t, col h*128+d); Kb [4096][512]; Vt [512][4096].
// O [2048][2048] batch-local. Block 256 thr = 4 waves; 64 q rows per block.
// ---------------------------------------------------------------------------
__global__ __launch_bounds__(256)
void attn_kernel(const s16* __restrict__ Q, const s16* __restrict__ Kb,
                 const s16* __restrict__ Vt, s16* __restrict__ O, int b)
{
    __shared__ s16 Ks[32][136];
    __shared__ s16 Vs[128][40];
    __shared__ s16 Ps[4][16][40];

    int h = blockIdx.y, g = h >> 2;
    int t0 = blockIdx.x * 64;
    int tid = threadIdx.x, lane = tid & 63, wv = tid >> 6;
    int fr = lane & 15, fq = lane >> 4;
    int tw = t0 + wv * 16;

    const float scale = 0.08838834764831845f;   // 128^-0.5
    const float NEG = -1e9f;

    short8 qf[4];
    {
        const s16* qrow = Q + (size_t)(b * 2048 + tw + fr) * 2048 + h * 128 + fq * 8;
        qf[0] = *(const short8*)(qrow);
        qf[1] = *(const short8*)(qrow + 32);
        qf[2] = *(const short8*)(qrow + 64);
        qf[3] = *(const short8*)(qrow + 96);
    }

    f32x4 Oacc[8] = {};
    float m_r[4], l_r[4];
    for (int r = 0; r < 4; r++) { m_r[r] = NEG; l_r[r] = 0.0f; }

    int lo = t0 - 512; if (lo < 0) lo = 0;
    int c0   = lo >> 5;
    int cend = (t0 + 63) >> 5;
    int nch  = cend - c0 + 1 + (c0 > 0 ? 1 : 0);

    for (int ic = 0; ic < nch; ic++) {
        int cc = (c0 > 0) ? (ic == 0 ? 0 : c0 + ic - 1) : ic;
        int kbase = cc * 32;

        __syncthreads();
        for (int it = 0; it < 2; it++) {
            int idx = it * 2048 + tid * 8;
            int kr = idx >> 7, kc = idx & 127;
            *(short8*)&Ks[kr][kc] =
                *(const short8*)(Kb + (size_t)(b * 2048 + kbase + kr) * 512 + g * 128 + kc);
        }
        for (int it = 0; it < 2; it++) {
            int idx = it * 2048 + tid * 8;
            int d = idx >> 5, kc = idx & 31;
            *(short8*)&Vs[d][kc] =
                *(const short8*)(Vt + (size_t)(g * 128 + d) * 4096 + b * 2048 + kbase + kc);
        }
        __syncthreads();

        float sv[2][4];
        for (int kn = 0; kn < 2; kn++) {
            f32x4 sc4 = {0.f, 0.f, 0.f, 0.f};
            for (int dc = 0; dc < 4; dc++) {
                short8 kf = *(const short8*)&Ks[kn * 16 + fr][dc * 32 + fq * 8];
                sc4 = MFMA16(qf[dc], kf, sc4);
            }
            int j = kbase + kn * 16 + fr;
            for (int r = 0; r < 4; r++) {
                int t = tw + fq * 4 + r;
                bool ok = (j <= t) && ((j >= t - 512) || (j < 4));
                sv[kn][r] = ok ? sc4[r] * scale : NEG;
            }
        }

        float alpha[4], p0[4], p1[4];
        for (int r = 0; r < 4; r++) {
            float cm = fmaxf(sv[0][r], sv[1][r]);
            for (int off = 1; off < 16; off <<= 1)
                cm = fmaxf(cm, __shfl_xor(cm, off));
            float nm = fmaxf(m_r[r], cm);
            alpha[r] = __expf(m_r[r] - nm);
            p0[r] = __expf(sv[0][r] - nm);
            p1[r] = __expf(sv[1][r] - nm);
            float ps = p0[r] + p1[r];
            for (int off = 1; off < 16; off <<= 1)
                ps += __shfl_xor(ps, off);
            l_r[r] = l_r[r] * alpha[r] + ps;
            m_r[r] = nm;
        }
        for (int n0 = 0; n0 < 8; n0++)
            for (int r = 0; r < 4; r++)
                Oacc[n0][r] *= alpha[r];

        for (int r = 0; r < 4; r++) {
            Ps[wv][fq * 4 + r][fr]      = f2bf(p0[r]);
            Ps[wv][fq * 4 + r][16 + fr] = f2bf(p1[r]);
        }
        __syncthreads();
        short8 pf = *(const short8*)&Ps[wv][fr][fq * 8];

        for (int n0 = 0; n0 < 8; n0++) {
            short8 vf = *(const short8*)&Vs[n0 * 16 + fr][fq * 8];
            Oacc[n0] = MFMA16(pf, vf, Oacc[n0]);
        }
    }

    float invl[4];
    for (int r = 0; r < 4; r++) invl[r] = 1.0f / l_r[r];
    for (int n0 = 0; n0 < 8; n0++)
        for (int r = 0; r < 4; r++) {
            int t = tw + fq * 4 + r;
            O[(size_t)t * 2048 + h * 128 + n0 * 16 + fr] =
                f2bf(Oacc[n0][r] * invl[r]);
        }
}

// ---------------------------------------------------------------------------
// Launcher (see workspace map at top).
// ---------------------------------------------------------------------------
extern "C" void kernel_launch(void* const* d_in, const int* in_sizes, int n_in,
                              void* d_out, int out_size, void* d_ws, size_t ws_size,
                              hipStream_t stream)
{
    const float* x  = (const float*)d_in[0];
    const float* Wq = (const float*)d_in[1];
    const float* bq = (const float*)d_in[2];
    const float* Wk = (const float*)d_in[3];
    const float* bk = (const float*)d_in[4];
    const float* Wv = (const float*)d_in[5];
    const float* bv = (const float*)d_in[6];
    const float* Wo = (const float*)d_in[7];
    const float* bo = (const float*)d_in[8];
    float* out = (float*)d_out;

    if (ws_size < 33554432) return;

    char* ws = (char*)d_ws;
    s16* Wqt = (s16*)(ws + 0);            // [2048][2048] bf16 (8 MB)
    s16* Wkt = (s16*)(ws + 0);            // [512][2048]  (2 MB, after Q GEMM)
    s16* Wvt = (s16*)(ws + 2097152);      // [512][2048]  (2 MB)
    s16* Wot = (s16*)(ws + 0);            // [2048][2048] (8 MB, after K/V GEMMs)
    s16* Qb  = (s16*)(ws + 8388608);      // [4096][2048] (16 MB)
    s16* Kb  = (s16*)(ws + 25165824);     // [4096][512]  (4 MB)
    s16* Vt  = (s16*)(ws + 29360128);     // [512][4096]  (4 MB)
    s16* At1 = (s16*)(ws + 8388608);      // [2048][2048] (8 MB) = dead Qb rows 0..2047
    s16* At0 = (s16*)((char*)d_out + 16777216);   // bf16 scratch in d_out batch-1 half

    // Q projection
    castT<<<dim3(64, 64), 256, 0, stream>>>(Wq, Wqt, 2048, 2048);
    gemm128<1, 0><<<dim3(32, 16), 256, 0, stream>>>(x, Wqt, bq, Qb, 4096, 2048, 2048, 0, 0);
    rope_kernel<<<16384, 256, 0, stream>>>(Qb, 16);

    // K projection
    castT<<<dim3(16, 64), 256, 0, stream>>>(Wk, Wkt, 2048, 512);
    gemm128<1, 0><<<dim3(32, 4), 256, 0, stream>>>(x, Wkt, bk, Kb, 4096, 512, 2048, 0, 0);
    rope_kernel<<<4096, 256, 0, stream>>>(Kb, 4);

    // V projection (transposed out)
    castT<<<dim3(16, 64), 256, 0, stream>>>(Wv, Wvt, 2048, 512);
    gemm128<1, 0><<<dim3(32, 4), 256, 0, stream>>>(x, Wvt, bv, Vt, 4096, 512, 2048, 1, 4096);

    // O weight
    castT<<<dim3(64, 64), 256, 0, stream>>>(Wo, Wot, 2048, 2048);

    // batch 0: attention -> At0 (d_out scratch), O-proj -> out[0, 16.8M)
    attn_kernel<<<dim3(32, 16), 256, 0, stream>>>(Qb, Kb, Vt, At0, 0);
    gemm128<0, 1><<<dim3(16, 16), 256, 0, stream>>>(At0, Wot, bo, out, 2048, 2048, 2048, 0, 0);

    // batch 1: attention -> At1 (dead Qb rows), O-proj -> out[16.8M, 33.5M)
    attn_kernel<<<dim3(32, 16), 256, 0, stream>>>(Qb, Kb, Vt, At1, 1);
    gemm128<0, 1><<<dim3(16, 16), 256, 0, stream>>>(At1, Wot, bo, out + 4194304, 2048, 2048, 2048, 0, 0);
}

// Round 6
// 413.533 us; speedup vs baseline: 1.8032x; 1.3974x over previous
//
#include <hip/hip_runtime.h>
#include <hip/hip_bf16.h>
#include <cstdint>
#include <cstddef>

// ---------------------------------------------------------------------------
// MaskedSelfAttention: B=2, T=2048, C=2048, NH=16, NG=4, D=128
// sliding window 512 + sink 4, RoPE base 10000, pos 0.
// fp32 I/O; bf16 MFMA internally (fp32 accum); m97-style global_load_lds GEMMs.
// Workspace (32 MB), time-multiplexed:
//   [0,16M):  xb [4096][2048] bf16  -> later At [2][2048][2048] bf16
//   [16,24M): Wqt (8M) -> Wkvt (4M) -> Wot (8M)
//   [24,28M): Kb [4096][512] bf16
//   [28,32M): Vt [512][4096] bf16
// Qb [4096][2048] bf16 lives in d_out's first 16.78 MB (dead before O-GEMM).
// ---------------------------------------------------------------------------

typedef short s16;
typedef short short8 __attribute__((ext_vector_type(8)));
typedef float f32x4  __attribute__((ext_vector_type(4)));

#define MFMA16(a, b, c) __builtin_amdgcn_mfma_f32_16x16x32_bf16((a), (b), (c), 0, 0, 0)

__device__ __forceinline__ float bf2f(s16 u) {
    union { float f; uint32_t i; } v;
    v.i = ((uint32_t)(uint16_t)u) << 16;
    return v.f;
}
__device__ __forceinline__ s16 f2bf(float f) {
    union { float f; uint32_t i; } v;
    v.f = f;
    uint32_t r = v.i + 0x7FFFu + ((v.i >> 16) & 1u);   // RNE
    return (s16)(r >> 16);
}

// async global->LDS, 16 B per lane; LDS dest = wave-uniform base + lane*16
__device__ __forceinline__ void gload16(const s16* g, s16* l) {
    __builtin_amdgcn_global_load_lds(
        (const __attribute__((address_space(1))) void*)g,
        (__attribute__((address_space(3))) void*)l, 16, 0, 0);
}

// ---------------------------------------------------------------------------
// Elementwise fp32 -> bf16 cast (8 elems/thread).
// ---------------------------------------------------------------------------
__global__ __launch_bounds__(256)
void cast_bf16(const float* __restrict__ in, s16* __restrict__ out)
{
    size_t i = ((size_t)blockIdx.x * 256 + threadIdx.x) * 8;
    f32x4 f0 = *(const f32x4*)(in + i);
    f32x4 f1 = *(const f32x4*)(in + i + 4);
    short8 h;
    h[0]=f2bf(f0[0]); h[1]=f2bf(f0[1]); h[2]=f2bf(f0[2]); h[3]=f2bf(f0[3]);
    h[4]=f2bf(f1[0]); h[5]=f2bf(f1[1]); h[6]=f2bf(f1[2]); h[7]=f2bf(f1[3]);
    *(short8*)(out + i) = h;
}

// ---------------------------------------------------------------------------
// Transpose + cast: in fp32 [K][N] -> out bf16 [N][K].  32x32 tiles.
// ---------------------------------------------------------------------------
__global__ __launch_bounds__(256)
void castT(const float* __restrict__ in, s16* __restrict__ out, int K, int N)
{
    __shared__ float t[32][33];
    int n0 = blockIdx.x * 32, k0 = blockIdx.y * 32;
    int tx = threadIdx.x & 31, ty = threadIdx.x >> 5;
    for (int i = 0; i < 32; i += 8)
        t[ty + i][tx] = in[(size_t)(k0 + ty + i) * N + n0 + tx];
    __syncthreads();
    for (int i = 0; i < 32; i += 8)
        out[(size_t)(n0 + ty + i) * K + k0 + tx] = f2bf(t[tx][ty + i]);
}

// ---------------------------------------------------------------------------
// GEMM: out[m][n] = sum_k A[m][k] * Bt[n][k] + bias[n]
// A bf16 [M][K]; Bt bf16 [N][K]. Tile 128x128, BK=32, 4 waves, wave=64x64.
// Staging via global_load_lds width-16 into flat [row][32] LDS (m97).
// MODE 0: bf16 out[m*N+n].  MODE 1: KV split (n<512 -> Kb bf16 [m][512];
//   n>=512 -> Vt bf16 [n-512][4096] transposed, bias2).  MODE 2: fp32 out.
// mfma_f32_16x16x32_bf16 layouts (verified m89/m91):
//   A-frag: A[m=lane&15][k=(lane>>4)*8+j]; B-frag: B[k=(lane>>4)*8+j][n=lane&15]
//   C/D:    row=(lane>>4)*4+reg, col=lane&15
// ---------------------------------------------------------------------------
template <int MODE>
__global__ __launch_bounds__(256)
void gemm_lds(const s16* __restrict__ A, const s16* __restrict__ Bt,
              const float* __restrict__ bias, const float* __restrict__ bias2,
              void* __restrict__ outp, void* __restrict__ outp2,
              int M, int N, int K)
{
    __shared__ s16 As[128 * 32];
    __shared__ s16 Bs[128 * 32];

    const int tid  = threadIdx.x;
    const int m0   = blockIdx.x * 128, n0 = blockIdx.y * 128;
    const int lane = tid & 63, wv = tid >> 6;
    const int wm   = (wv >> 1) * 64, wn = (wv & 1) * 64;
    const int fr   = lane & 15, fq = lane >> 4;

    // staging: wave wv covers rows [wv*16, wv*16+16) and +64; lane l ->
    // row +l/4, k-off (l&3)*8. LDS byte offset = row0*64 + lane*16 (flat).
    const int srow = wv * 16 + (lane >> 2);
    const int koff = (lane & 3) * 8;
    const s16* ga0 = A  + (size_t)(m0 + srow) * K + koff;
    const s16* ga1 = A  + (size_t)(m0 + 64 + srow) * K + koff;
    const s16* gb0 = Bt + (size_t)(n0 + srow) * K + koff;
    const s16* gb1 = Bt + (size_t)(n0 + 64 + srow) * K + koff;
    s16* la0 = &As[(wv * 16) * 32];
    s16* la1 = &As[(64 + wv * 16) * 32];
    s16* lb0 = &Bs[(wv * 16) * 32];
    s16* lb1 = &Bs[(64 + wv * 16) * 32];

    // fragment LDS pointers (constant over k-loop)
    const s16* pa[4];
    const s16* pb[4];
    #pragma unroll
    for (int i = 0; i < 4; i++) {
        pa[i] = &As[(wm + i * 16 + fr) * 32 + fq * 8];
        pb[i] = &Bs[(wn + i * 16 + fr) * 32 + fq * 8];
    }

    f32x4 acc[4][4] = {};

    for (int k0 = 0; k0 < K; k0 += 32) {
        __syncthreads();
        gload16(ga0 + k0, la0);
        gload16(ga1 + k0, la1);
        gload16(gb0 + k0, lb0);
        gload16(gb1 + k0, lb1);
        __syncthreads();

        short8 af[4], bfr[4];
        #pragma unroll
        for (int i = 0; i < 4; i++) af[i] = *(const short8*)pa[i];
        #pragma unroll
        for (int i = 0; i < 4; i++) bfr[i] = *(const short8*)pb[i];

        #pragma unroll
        for (int mi = 0; mi < 4; mi++)
            #pragma unroll
            for (int ni = 0; ni < 4; ni++)
                acc[mi][ni] = MFMA16(af[mi], bfr[ni], acc[mi][ni]);
    }

    #pragma unroll
    for (int mi = 0; mi < 4; mi++)
        #pragma unroll
        for (int ni = 0; ni < 4; ni++)
            #pragma unroll
            for (int r = 0; r < 4; r++) {
                int m = m0 + wm + mi * 16 + fq * 4 + r;
                int n = n0 + wn + ni * 16 + fr;
                float v = acc[mi][ni][r];
                if (MODE == 0) {
                    ((s16*)outp)[(size_t)m * N + n] = f2bf(v + bias[n]);
                } else if (MODE == 1) {
                    if (n < 512)
                        ((s16*)outp)[(size_t)m * 512 + n] = f2bf(v + bias[n]);
                    else
                        ((s16*)outp2)[(size_t)(n - 512) * 4096 + m] = f2bf(v + bias2[n - 512]);
                } else {
                    ((float*)outp)[(size_t)m * N + n] = v + bias[n];
                }
            }
}

// ---------------------------------------------------------------------------
// RoPE in-place on bf16 buf [4096][nheads*128]; pairs (i, i+64); pos 0.
// ---------------------------------------------------------------------------
__global__ __launch_bounds__(256)
void rope_kernel(s16* __restrict__ buf, int nheads)
{
    int idx = blockIdx.x * 256 + threadIdx.x;
    int i   = idx & 63;
    int hi  = idx >> 6;
    int h   = hi % nheads;
    int row = hi / nheads;
    int t   = row & 2047;

    float inv_freq = (float)(1.0 / pow(10000.0, (double)i * (1.0 / 64.0)));
    float ang = (float)t * inv_freq;
    float c = cosf(ang);
    float s = sinf(ang);

    size_t base = (size_t)row * ((size_t)nheads * 128) + (size_t)h * 128 + i;
    float x1 = bf2f(buf[base]);
    float x2 = bf2f(buf[base + 64]);
    buf[base]      = f2bf(x1 * c - x2 * s);
    buf[base + 64] = f2bf(x1 * s + x2 * c);
}

// ---------------------------------------------------------------------------
// Flash attention, sliding window + sink; both batches in one launch (z=b).
// Q [4096][2048] bf16 (row b*2048+t, col h*128+d); Kb [4096][512]; Vt [512][4096].
// At [2][2048][2048] bf16. Block 256 thr = 4 waves; 64 q rows per block.
// ---------------------------------------------------------------------------
__global__ __launch_bounds__(256)
void attn_kernel(const s16* __restrict__ Q, const s16* __restrict__ Kb,
                 const s16* __restrict__ Vt, s16* __restrict__ At)
{
    __shared__ s16 Ks[32][136];
    __shared__ s16 Vs[128][40];
    __shared__ s16 Ps[4][16][40];

    int b = blockIdx.z;
    int h = blockIdx.y, g = h >> 2;
    int t0 = blockIdx.x * 64;
    int tid = threadIdx.x, lane = tid & 63, wv = tid >> 6;
    int fr = lane & 15, fq = lane >> 4;
    int tw = t0 + wv * 16;
    s16* O = At + (size_t)b * 4194304;

    const float scale = 0.08838834764831845f;   // 128^-0.5
    const float NEG = -1e9f;

    short8 qf[4];
    {
        const s16* qrow = Q + (size_t)(b * 2048 + tw + fr) * 2048 + h * 128 + fq * 8;
        qf[0] = *(const short8*)(qrow);
        qf[1] = *(const short8*)(qrow + 32);
        qf[2] = *(const short8*)(qrow + 64);
        qf[3] = *(const short8*)(qrow + 96);
    }

    f32x4 Oacc[8] = {};
    float m_r[4], l_r[4];
    for (int r = 0; r < 4; r++) { m_r[r] = NEG; l_r[r] = 0.0f; }

    int lo = t0 - 512; if (lo < 0) lo = 0;
    int c0   = lo >> 5;
    int cend = (t0 + 63) >> 5;
    int nch  = cend - c0 + 1 + (c0 > 0 ? 1 : 0);

    for (int ic = 0; ic < nch; ic++) {
        int cc = (c0 > 0) ? (ic == 0 ? 0 : c0 + ic - 1) : ic;
        int kbase = cc * 32;

        __syncthreads();
        for (int it = 0; it < 2; it++) {
            int idx = it * 2048 + tid * 8;
            int kr = idx >> 7, kc = idx & 127;
            *(short8*)&Ks[kr][kc] =
                *(const short8*)(Kb + (size_t)(b * 2048 + kbase + kr) * 512 + g * 128 + kc);
        }
        for (int it = 0; it < 2; it++) {
            int idx = it * 2048 + tid * 8;
            int d = idx >> 5, kc = idx & 31;
            *(short8*)&Vs[d][kc] =
                *(const short8*)(Vt + (size_t)(g * 128 + d) * 4096 + b * 2048 + kbase + kc);
        }
        __syncthreads();

        float sv[2][4];
        for (int kn = 0; kn < 2; kn++) {
            f32x4 sc4 = {0.f, 0.f, 0.f, 0.f};
            for (int dc = 0; dc < 4; dc++) {
                short8 kf = *(const short8*)&Ks[kn * 16 + fr][dc * 32 + fq * 8];
                sc4 = MFMA16(qf[dc], kf, sc4);
            }
            int j = kbase + kn * 16 + fr;
            for (int r = 0; r < 4; r++) {
                int t = tw + fq * 4 + r;
                bool ok = (j <= t) && ((j >= t - 512) || (j < 4));
                sv[kn][r] = ok ? sc4[r] * scale : NEG;
            }
        }

        float alpha[4], p0[4], p1[4];
        for (int r = 0; r < 4; r++) {
            float cm = fmaxf(sv[0][r], sv[1][r]);
            for (int off = 1; off < 16; off <<= 1)
                cm = fmaxf(cm, __shfl_xor(cm, off));
            float nm = fmaxf(m_r[r], cm);
            alpha[r] = __expf(m_r[r] - nm);
            p0[r] = __expf(sv[0][r] - nm);
            p1[r] = __expf(sv[1][r] - nm);
            float ps = p0[r] + p1[r];
            for (int off = 1; off < 16; off <<= 1)
                ps += __shfl_xor(ps, off);
            l_r[r] = l_r[r] * alpha[r] + ps;
            m_r[r] = nm;
        }
        for (int n0 = 0; n0 < 8; n0++)
            for (int r = 0; r < 4; r++)
                Oacc[n0][r] *= alpha[r];

        for (int r = 0; r < 4; r++) {
            Ps[wv][fq * 4 + r][fr]      = f2bf(p0[r]);
            Ps[wv][fq * 4 + r][16 + fr] = f2bf(p1[r]);
        }
        __syncthreads();
        short8 pf = *(const short8*)&Ps[wv][fr][fq * 8];

        for (int n0 = 0; n0 < 8; n0++) {
            short8 vf = *(const short8*)&Vs[n0 * 16 + fr][fq * 8];
            Oacc[n0] = MFMA16(pf, vf, Oacc[n0]);
        }
    }

    float invl[4];
    for (int r = 0; r < 4; r++) invl[r] = 1.0f / l_r[r];
    for (int n0 = 0; n0 < 8; n0++)
        for (int r = 0; r < 4; r++) {
            int t = tw + fq * 4 + r;
            O[(size_t)t * 2048 + h * 128 + n0 * 16 + fr] =
                f2bf(Oacc[n0][r] * invl[r]);
        }
}

// ---------------------------------------------------------------------------
// Launcher (workspace map at top of file).
// ---------------------------------------------------------------------------
extern "C" void kernel_launch(void* const* d_in, const int* in_sizes, int n_in,
                              void* d_out, int out_size, void* d_ws, size_t ws_size,
                              hipStream_t stream)
{
    const float* x  = (const float*)d_in[0];
    const float* Wq = (const float*)d_in[1];
    const float* bq = (const float*)d_in[2];
    const float* Wk = (const float*)d_in[3];
    const float* bk = (const float*)d_in[4];
    const float* Wv = (const float*)d_in[5];
    const float* bv = (const float*)d_in[6];
    const float* Wo = (const float*)d_in[7];
    const float* bo = (const float*)d_in[8];
    float* out = (float*)d_out;

    if (ws_size < 33554432) return;

    char* ws = (char*)d_ws;
    s16* xb   = (s16*)(ws + 0);           // [4096][2048] bf16 (16 MB)
    s16* At   = (s16*)(ws + 0);           // [2][2048][2048] bf16 (16 MB, after xb dies)
    s16* Wqt  = (s16*)(ws + 16777216);    // [2048][2048] (8 MB)
    s16* Wkvt = (s16*)(ws + 16777216);    // [1024][2048] (4 MB)
    s16* Wot  = (s16*)(ws + 16777216);    // [2048][2048] (8 MB)
    s16* Kb   = (s16*)(ws + 25165824);    // [4096][512]  (4 MB)
    s16* Vt   = (s16*)(ws + 29360128);    // [512][4096]  (4 MB)
    s16* Qb   = (s16*)d_out;              // [4096][2048] bf16 in d_out (16.78 MB)

    // x -> bf16
    cast_bf16<<<4096, 256, 0, stream>>>(x, xb);

    // Q projection (Qb in d_out scratch) + RoPE
    castT<<<dim3(64, 64), 256, 0, stream>>>(Wq, Wqt, 2048, 2048);
    gemm_lds<0><<<dim3(32, 16), 256, 0, stream>>>(xb, Wqt, bq, nullptr, Qb, nullptr,
                                                  4096, 2048, 2048);
    rope_kernel<<<16384, 256, 0, stream>>>(Qb, 16);

    // K+V combined projection (Wkvt rows 0-511 = Wk^T, 512-1023 = Wv^T)
    castT<<<dim3(16, 64), 256, 0, stream>>>(Wk, Wkvt, 2048, 512);
    castT<<<dim3(16, 64), 256, 0, stream>>>(Wv, Wkvt + (size_t)512 * 2048, 2048, 512);
    gemm_lds<1><<<dim3(32, 8), 256, 0, stream>>>(xb, Wkvt, bk, bv, Kb, Vt,
                                                 4096, 1024, 2048);
    rope_kernel<<<4096, 256, 0, stream>>>(Kb, 4);

    // O weight transpose (Wkvt dead after KV GEMM)
    castT<<<dim3(64, 64), 256, 0, stream>>>(Wo, Wot, 2048, 2048);

    // attention, both batches (xb dead -> At区 reused)
    attn_kernel<<<dim3(32, 16, 2), 256, 0, stream>>>(Qb, Kb, Vt, At);

    // output projection: At [4096][2048] x Wot -> out fp32 [4096][2048]
    gemm_lds<2><<<dim3(32, 16), 256, 0, stream>>>(At, Wot, bo, nullptr, out, nullptr,
                                                  4096, 2048, 2048);
}

// Round 7
// 369.223 us; speedup vs baseline: 2.0196x; 1.1200x over previous
//
#include <hip/hip_runtime.h>
#include <hip/hip_bf16.h>
#include <cstdint>
#include <cstddef>

// ---------------------------------------------------------------------------
// MaskedSelfAttention: B=2, T=2048, C=2048, NH=16, NG=4, D=128
// sliding window 512 + sink 4, RoPE base 10000, pos 0.
// fp32 I/O; bf16 MFMA internally (fp32 accum).
// Workspace (32 MB):
//   [0,16M):  xb [4096][2048] bf16 -> later At [2][2048][2048] bf16
//   [16,28M): Wqkvt [3072][2048] bf16 -> later Wot [2048][2048] (16-24M)
// d_out scratch (33.5 MB fp32, dead until final O-GEMM):
//   [0,16.78M): Qb [4096][2048] bf16
//   [16.78,20.97M): Kb [4096][512] bf16
//   [20.97,25.17M): Vt [512][4096] bf16
// ---------------------------------------------------------------------------

typedef short s16;
typedef short short8 __attribute__((ext_vector_type(8)));
typedef float f32x4  __attribute__((ext_vector_type(4)));

#define MFMA16(a, b, c) __builtin_amdgcn_mfma_f32_16x16x32_bf16((a), (b), (c), 0, 0, 0)

__device__ __forceinline__ float bf2f(s16 u) {
    union { float f; uint32_t i; } v;
    v.i = ((uint32_t)(uint16_t)u) << 16;
    return v.f;
}
__device__ __forceinline__ s16 f2bf(float f) {
    union { float f; uint32_t i; } v;
    v.f = f;
    uint32_t r = v.i + 0x7FFFu + ((v.i >> 16) & 1u);   // RNE
    return (s16)(r >> 16);
}

// async global->LDS, 16 B per lane; LDS dest = wave-uniform base + lane*16
__device__ __forceinline__ void gload16(const s16* g, s16* l) {
    __builtin_amdgcn_global_load_lds(
        (const __attribute__((address_space(1))) void*)g,
        (__attribute__((address_space(3))) void*)l, 16, 0, 0);
}

// ---------------------------------------------------------------------------
// Elementwise fp32 -> bf16 cast (8 elems/thread).
// ---------------------------------------------------------------------------
__global__ __launch_bounds__(256)
void cast_bf16(const float* __restrict__ in, s16* __restrict__ out)
{
    size_t i = ((size_t)blockIdx.x * 256 + threadIdx.x) * 8;
    f32x4 f0 = *(const f32x4*)(in + i);
    f32x4 f1 = *(const f32x4*)(in + i + 4);
    short8 h;
    h[0]=f2bf(f0[0]); h[1]=f2bf(f0[1]); h[2]=f2bf(f0[2]); h[3]=f2bf(f0[3]);
    h[4]=f2bf(f1[0]); h[5]=f2bf(f1[1]); h[6]=f2bf(f1[2]); h[7]=f2bf(f1[3]);
    *(short8*)(out + i) = h;
}

// ---------------------------------------------------------------------------
// Transpose+cast all three QKV weights into Wqkvt [3072][2048]:
//   rows 0-2047 = Wq^T, 2048-2559 = Wk^T, 2560-3071 = Wv^T. K=2048 fixed.
// ---------------------------------------------------------------------------
__global__ __launch_bounds__(256)
void castT3(const float* __restrict__ Wq, const float* __restrict__ Wk,
            const float* __restrict__ Wv, s16* __restrict__ out)
{
    int z = blockIdx.z;
    const float* in; s16* dst; int N;
    if (z == 0)      { in = Wq; dst = out;                        N = 2048; }
    else if (z == 1) { in = Wk; dst = out + (size_t)2048 * 2048;  N = 512; }
    else             { in = Wv; dst = out + (size_t)2560 * 2048;  N = 512; }
    int n0 = blockIdx.x * 32, k0 = blockIdx.y * 32;
    if (n0 >= N) return;

    __shared__ float t[32][33];
    int tx = threadIdx.x & 31, ty = threadIdx.x >> 5;
    for (int i = 0; i < 32; i += 8)
        t[ty + i][tx] = in[(size_t)(k0 + ty + i) * N + n0 + tx];
    __syncthreads();
    for (int i = 0; i < 32; i += 8)
        dst[(size_t)(n0 + ty + i) * 2048 + k0 + tx] = f2bf(t[tx][ty + i]);
}

// ---------------------------------------------------------------------------
// Single-weight transpose+cast: fp32 [2048][2048] -> bf16 [2048][2048]^T.
// ---------------------------------------------------------------------------
__global__ __launch_bounds__(256)
void castT(const float* __restrict__ in, s16* __restrict__ out)
{
    __shared__ float t[32][33];
    int n0 = blockIdx.x * 32, k0 = blockIdx.y * 32;
    int tx = threadIdx.x & 31, ty = threadIdx.x >> 5;
    for (int i = 0; i < 32; i += 8)
        t[ty + i][tx] = in[(size_t)(k0 + ty + i) * 2048 + n0 + tx];
    __syncthreads();
    for (int i = 0; i < 32; i += 8)
        out[(size_t)(n0 + ty + i) * 2048 + k0 + tx] = f2bf(t[tx][ty + i]);
}

// ---------------------------------------------------------------------------
// GEMM: out = A[M][K] x Bt[N][K]^T + bias. m97 staging (global_load_lds w16),
// tile 128x128, BK=32, 4 waves, wave = 64x64 (4x4 MFMA frags).
// MODE 0: QKV split epilogue (n<2048 -> Qb bf16; n<2560 -> Kb bf16;
//         else Vt bf16 transposed).  MODE 2: fp32 out + bias.
// mfma_f32_16x16x32_bf16 layouts (verified m89/m91):
//   A-frag: A[m=lane&15][k=(lane>>4)*8+j]; B-frag: B[k=(lane>>4)*8+j][n=lane&15]
//   C/D:    row=(lane>>4)*4+reg, col=lane&15
// ---------------------------------------------------------------------------
template <int MODE>
__global__ __launch_bounds__(256)
void gemm_lds(const s16* __restrict__ A, const s16* __restrict__ Bt,
              const float* __restrict__ b0, const float* __restrict__ b1,
              const float* __restrict__ b2,
              void* __restrict__ o0, void* __restrict__ o1, void* __restrict__ o2,
              int M, int N, int K)
{
    __shared__ s16 As[128 * 32];
    __shared__ s16 Bs[128 * 32];

    const int tid  = threadIdx.x;
    const int m0   = blockIdx.x * 128, n0 = blockIdx.y * 128;
    const int lane = tid & 63, wv = tid >> 6;
    const int wm   = (wv >> 1) * 64, wn = (wv & 1) * 64;
    const int fr   = lane & 15, fq = lane >> 4;

    const int srow = wv * 16 + (lane >> 2);
    const int koff = (lane & 3) * 8;
    const s16* ga0 = A  + (size_t)(m0 + srow) * K + koff;
    const s16* ga1 = A  + (size_t)(m0 + 64 + srow) * K + koff;
    const s16* gb0 = Bt + (size_t)(n0 + srow) * K + koff;
    const s16* gb1 = Bt + (size_t)(n0 + 64 + srow) * K + koff;
    s16* la0 = &As[(wv * 16) * 32];
    s16* la1 = &As[(64 + wv * 16) * 32];
    s16* lb0 = &Bs[(wv * 16) * 32];
    s16* lb1 = &Bs[(64 + wv * 16) * 32];

    const s16* pa[4];
    const s16* pb[4];
    #pragma unroll
    for (int i = 0; i < 4; i++) {
        pa[i] = &As[(wm + i * 16 + fr) * 32 + fq * 8];
        pb[i] = &Bs[(wn + i * 16 + fr) * 32 + fq * 8];
    }

    f32x4 acc[4][4] = {};

    for (int k0 = 0; k0 < K; k0 += 32) {
        __syncthreads();
        gload16(ga0 + k0, la0);
        gload16(ga1 + k0, la1);
        gload16(gb0 + k0, lb0);
        gload16(gb1 + k0, lb1);
        __syncthreads();

        short8 af[4], bfr[4];
        #pragma unroll
        for (int i = 0; i < 4; i++) af[i] = *(const short8*)pa[i];
        #pragma unroll
        for (int i = 0; i < 4; i++) bfr[i] = *(const short8*)pb[i];

        #pragma unroll
        for (int mi = 0; mi < 4; mi++)
            #pragma unroll
            for (int ni = 0; ni < 4; ni++)
                acc[mi][ni] = MFMA16(af[mi], bfr[ni], acc[mi][ni]);
    }

    #pragma unroll
    for (int mi = 0; mi < 4; mi++)
        #pragma unroll
        for (int ni = 0; ni < 4; ni++)
            #pragma unroll
            for (int r = 0; r < 4; r++) {
                int m = m0 + wm + mi * 16 + fq * 4 + r;
                int n = n0 + wn + ni * 16 + fr;
                float v = acc[mi][ni][r];
                if (MODE == 0) {
                    if (n < 2048)
                        ((s16*)o0)[(size_t)m * 2048 + n] = f2bf(v + b0[n]);
                    else if (n < 2560)
                        ((s16*)o1)[(size_t)m * 512 + (n - 2048)] = f2bf(v + b1[n - 2048]);
                    else
                        ((s16*)o2)[(size_t)(n - 2560) * 4096 + m] = f2bf(v + b2[n - 2560]);
                } else {
                    ((float*)o0)[(size_t)m * N + n] = v + b0[n];
                }
            }
}

// ---------------------------------------------------------------------------
// Fused RoPE for Q (16 heads) and K (4 heads), in-place, pos 0.
// Blocks [0,16384) -> Qb rows; [16384,20480) -> Kb rows.
// ---------------------------------------------------------------------------
__global__ __launch_bounds__(256)
void rope2_kernel(s16* __restrict__ Qb, s16* __restrict__ Kb)
{
    int bx = blockIdx.x;
    s16* buf; int nheads; int idx;
    if (bx < 16384) { buf = Qb; nheads = 16; idx = bx * 256 + threadIdx.x; }
    else            { buf = Kb; nheads = 4;  idx = (bx - 16384) * 256 + threadIdx.x; }

    int i   = idx & 63;
    int hi  = idx >> 6;
    int h   = hi % nheads;
    int row = hi / nheads;
    int t   = row & 2047;

    float inv_freq = __powf(10000.0f, -(float)i * (1.0f / 64.0f));
    float ang = (float)t * inv_freq;
    float c = cosf(ang);
    float s = sinf(ang);

    size_t base = (size_t)row * ((size_t)nheads * 128) + (size_t)h * 128 + i;
    float x1 = bf2f(buf[base]);
    float x2 = bf2f(buf[base + 64]);
    buf[base]      = f2bf(x1 * c - x2 * s);
    buf[base + 64] = f2bf(x1 * s + x2 * c);
}

// ---------------------------------------------------------------------------
// Flash attention, sliding window + sink; both batches (z=b).
// Double-buffered K/V (VGPR prefetch), 1 barrier per chunk, heavy-first order.
// Q [4096][2048] bf16; Kb [4096][512]; Vt [512][4096]; At [2][2048][2048].
// Block 256 thr = 4 waves; 64 q rows of one h; key chunks of 32.
// ---------------------------------------------------------------------------
__global__ __launch_bounds__(256)
void attn_kernel(const s16* __restrict__ Q, const s16* __restrict__ Kb,
                 const s16* __restrict__ Vt, s16* __restrict__ At)
{
    __shared__ s16 Ks[2][32][136];   // [buf][key][d]
    __shared__ s16 Vs[2][128][40];   // [buf][d][key]
    __shared__ s16 Ps[4][16][40];    // per-wave P (wave-private)

    int b = blockIdx.z;
    int h = blockIdx.y, g = h >> 2;
    int t0 = (31 - blockIdx.x) * 64;          // heavy blocks dispatch first
    int tid = threadIdx.x, lane = tid & 63, wv = tid >> 6;
    int fr = lane & 15, fq = lane >> 4;
    int tw = t0 + wv * 16;
    s16* O = At + (size_t)b * 4194304;

    const float scale = 0.08838834764831845f;   // 128^-0.5
    const float NEG = -1e9f;

    // per-thread staging geometry (2 chunks of work for K and V each)
    int kr[2], kc[2], vd[2], vc[2];
    const s16 *gK[2], *gV[2];
    #pragma unroll
    for (int it = 0; it < 2; it++) {
        int idx = it * 2048 + tid * 8;
        kr[it] = idx >> 7;  kc[it] = idx & 127;
        vd[it] = idx >> 5;  vc[it] = idx & 31;
        gK[it] = Kb + (size_t)(b * 2048 + kr[it]) * 512 + g * 128 + kc[it];
        gV[it] = Vt + (size_t)(g * 128 + vd[it]) * 4096 + b * 2048 + vc[it];
    }

    // Q A-frags for the whole kernel
    short8 qf[4];
    {
        const s16* qrow = Q + (size_t)(b * 2048 + tw + fr) * 2048 + h * 128 + fq * 8;
        qf[0] = *(const short8*)(qrow);
        qf[1] = *(const short8*)(qrow + 32);
        qf[2] = *(const short8*)(qrow + 64);
        qf[3] = *(const short8*)(qrow + 96);
    }

    f32x4 Oacc[8] = {};
    float m_r[4], l_r[4];
    #pragma unroll
    for (int r = 0; r < 4; r++) { m_r[r] = NEG; l_r[r] = 0.0f; }

    int lo = t0 - 512; if (lo < 0) lo = 0;
    int c0   = lo >> 5;
    int cend = (t0 + 63) >> 5;
    int nch  = cend - c0 + 1 + (c0 > 0 ? 1 : 0);

    #define CHUNKBASE(ic) ((((c0) > 0) ? ((ic) == 0 ? 0 : c0 + (ic) - 1) : (ic)) * 32)

    short8 kpre[2], vpre[2];
    {   // prefetch + store chunk 0 into buf 0
        int kb = CHUNKBASE(0);
        #pragma unroll
        for (int it = 0; it < 2; it++) {
            kpre[it] = *(const short8*)(gK[it] + (size_t)kb * 512);
            vpre[it] = *(const short8*)(gV[it] + kb);
        }
        #pragma unroll
        for (int it = 0; it < 2; it++) {
            *(short8*)&Ks[0][kr[it]][kc[it]] = kpre[it];
            *(short8*)&Vs[0][vd[it]][vc[it]] = vpre[it];
        }
    }
    __syncthreads();

    for (int ic = 0; ic < nch; ic++) {
        int cur = ic & 1;
        int kbase = CHUNKBASE(ic);
        bool pre = (ic + 1 < nch);
        if (pre) {
            int kb = CHUNKBASE(ic + 1);
            #pragma unroll
            for (int it = 0; it < 2; it++) {
                kpre[it] = *(const short8*)(gK[it] + (size_t)kb * 512);
                vpre[it] = *(const short8*)(gV[it] + kb);
            }
        }

        // S = Q K^T, two 16-key sub-tiles
        float sv[2][4];
        #pragma unroll
        for (int kn = 0; kn < 2; kn++) {
            f32x4 sc4 = {0.f, 0.f, 0.f, 0.f};
            #pragma unroll
            for (int dc = 0; dc < 4; dc++) {
                short8 kf = *(const short8*)&Ks[cur][kn * 16 + fr][dc * 32 + fq * 8];
                sc4 = MFMA16(qf[dc], kf, sc4);
            }
            int j = kbase + kn * 16 + fr;
            #pragma unroll
            for (int r = 0; r < 4; r++) {
                int t = tw + fq * 4 + r;
                bool ok = (j <= t) && ((j >= t - 512) || (j < 4));
                sv[kn][r] = ok ? sc4[r] * scale : NEG;
            }
        }

        // online softmax; row fq*4+r lives in lanes fq*16..fq*16+15
        float alpha[4], p0[4], p1[4];
        #pragma unroll
        for (int r = 0; r < 4; r++) {
            float cm = fmaxf(sv[0][r], sv[1][r]);
            for (int off = 1; off < 16; off <<= 1)
                cm = fmaxf(cm, __shfl_xor(cm, off));
            float nm = fmaxf(m_r[r], cm);
            alpha[r] = __expf(m_r[r] - nm);
            p0[r] = __expf(sv[0][r] - nm);
            p1[r] = __expf(sv[1][r] - nm);
            float ps = p0[r] + p1[r];
            for (int off = 1; off < 16; off <<= 1)
                ps += __shfl_xor(ps, off);
            l_r[r] = l_r[r] * alpha[r] + ps;
            m_r[r] = nm;
        }
        #pragma unroll
        for (int n0 = 0; n0 < 8; n0++)
            #pragma unroll
            for (int r = 0; r < 4; r++)
                Oacc[n0][r] *= alpha[r];

        // P: C/D layout -> A layout. Ps[wv] is wave-private: lgkm fence only.
        #pragma unroll
        for (int r = 0; r < 4; r++) {
            Ps[wv][fq * 4 + r][fr]      = f2bf(p0[r]);
            Ps[wv][fq * 4 + r][16 + fr] = f2bf(p1[r]);
        }
        __threadfence_block();
        short8 pf = *(const short8*)&Ps[wv][fr][fq * 8];

        #pragma unroll
        for (int n0 = 0; n0 < 8; n0++) {
            short8 vf = *(const short8*)&Vs[cur][n0 * 16 + fr][fq * 8];
            Oacc[n0] = MFMA16(pf, vf, Oacc[n0]);
        }

        if (pre) {
            #pragma unroll
            for (int it = 0; it < 2; it++) {
                *(short8*)&Ks[cur ^ 1][kr[it]][kc[it]] = kpre[it];
                *(short8*)&Vs[cur ^ 1][vd[it]][vc[it]] = vpre[it];
            }
            __syncthreads();
        }
    }

    float invl[4];
    #pragma unroll
    for (int r = 0; r < 4; r++) invl[r] = 1.0f / l_r[r];
    #pragma unroll
    for (int n0 = 0; n0 < 8; n0++)
        #pragma unroll
        for (int r = 0; r < 4; r++) {
            int t = tw + fq * 4 + r;
            O[(size_t)t * 2048 + h * 128 + n0 * 16 + fr] =
                f2bf(Oacc[n0][r] * invl[r]);
        }
}

// ---------------------------------------------------------------------------
// Launcher (memory map at top of file).
// ---------------------------------------------------------------------------
extern "C" void kernel_launch(void* const* d_in, const int* in_sizes, int n_in,
                              void* d_out, int out_size, void* d_ws, size_t ws_size,
                              hipStream_t stream)
{
    const float* x  = (const float*)d_in[0];
    const float* Wq = (const float*)d_in[1];
    const float* bq = (const float*)d_in[2];
    const float* Wk = (const float*)d_in[3];
    const float* bk = (const float*)d_in[4];
    const float* Wv = (const float*)d_in[5];
    const float* bv = (const float*)d_in[6];
    const float* Wo = (const float*)d_in[7];
    const float* bo = (const float*)d_in[8];
    float* out = (float*)d_out;

    if (ws_size < 33554432) return;

    char* ws = (char*)d_ws;
    s16* xb    = (s16*)(ws + 0);           // [4096][2048] bf16 (16 MB)
    s16* At    = (s16*)(ws + 0);           // [2][2048][2048] bf16 (after xb dies)
    s16* Wqkvt = (s16*)(ws + 16777216);    // [3072][2048] bf16 (12 MB)
    s16* Wot   = (s16*)(ws + 16777216);    // [2048][2048] bf16 (after QKV GEMM)
    s16* Qb    = (s16*)d_out;                              // [4096][2048] bf16
    s16* Kb    = (s16*)((char*)d_out + 16777216);          // [4096][512]  bf16
    s16* Vt    = (s16*)((char*)d_out + 20971520);          // [512][4096]  bf16

    // x -> bf16
    cast_bf16<<<4096, 256, 0, stream>>>(x, xb);

    // QKV weights -> Wqkvt (transposed bf16)
    castT3<<<dim3(64, 64, 3), 256, 0, stream>>>(Wq, Wk, Wv, Wqkvt);

    // fused QKV projection with split epilogue
    gemm_lds<0><<<dim3(32, 24), 256, 0, stream>>>(xb, Wqkvt, bq, bk, bv,
                                                  Qb, Kb, Vt, 4096, 3072, 2048);

    // RoPE on Q and K (one launch)
    rope2_kernel<<<20480, 256, 0, stream>>>(Qb, Kb);

    // O weight (overwrites Wqkvt; stream-ordered after QKV GEMM)
    castT<<<dim3(64, 64), 256, 0, stream>>>(Wo, Wot);

    // attention, both batches (xb dead -> At reuses its space)
    attn_kernel<<<dim3(32, 16, 2), 256, 0, stream>>>(Qb, Kb, Vt, At);

    // output projection: At [4096][2048] x Wot + bo -> out fp32
    gemm_lds<2><<<dim3(32, 16), 256, 0, stream>>>(At, Wot, bo, nullptr, nullptr,
                                                  out, nullptr, nullptr,
                                                  4096, 2048, 2048);
}